// Round 4
// baseline (2185.425 us; speedup 1.0000x reference)
//
#include <hip/hip_runtime.h>
#include <stdint.h>

#define NSEQ 512
#define XS 328   // xin row stride (shorts)
#define AS 136   // act row stride (shorts)
#define TS 516   // dts row stride (f32)
#define EPS 1e-5f

typedef short bfrag __attribute__((ext_vector_type(8)));
typedef float f4 __attribute__((ext_vector_type(4)));

__device__ __forceinline__ float bf2f(unsigned short u){ return __uint_as_float(((uint32_t)u)<<16); }
__device__ __forceinline__ unsigned short f2bf(float f){
  uint32_t u = __float_as_uint(f);
  u += 0x7FFFu + ((u>>16)&1u);   // RNE
  return (unsigned short)(u>>16);
}
__device__ __forceinline__ float tanh_fast(float v){
  float e = __expf(2.f*v);
  return 1.f - __fdividef(2.f, e+1.f);
}
// LDS-only barrier: does NOT drain vmcnt, so global prefetch loads and
// output stores stay in flight across it (unlike __syncthreads()).
__device__ __forceinline__ void lds_barrier(){
  asm volatile("s_waitcnt lgkmcnt(0)" ::: "memory");
  __builtin_amdgcn_s_barrier();
  __builtin_amdgcn_sched_barrier(0);
}

// One hidden layer for 16 rows. Wave w owns cols [32w, 32w+32).
// A: lane holds row=lc, k=lg*8+j (+32*kt). C: col=lc (+16*nt), row=4*lg+g.
template<int NKT>
__device__ __forceinline__ void mlp_layer(
    const unsigned short* __restrict__ inb, const int istride,
    const bfrag (&B)[2][NKT],
    const float (&br)[2], const float (&gr)[2], const float (&ber)[2],
    unsigned short* __restrict__ actb, float* __restrict__ part,
    const int w, const int l, const int lg, const int lc)
{
  const int aoff = lc*istride + lg*8;
  bfrag a[NKT];
#pragma unroll
  for (int kt=0; kt<NKT; ++kt) a[kt] = *(const bfrag*)(inb + aoff + kt*32);
  const f4 z4 = {0,0,0,0};
  f4 acc0a=z4, acc0b=z4, acc1a=z4, acc1b=z4;   // even/odd kt chains
#pragma unroll
  for (int kt=0; kt<NKT; ++kt){
    if (kt & 1){
      acc0b = __builtin_amdgcn_mfma_f32_16x16x32_bf16(a[kt], B[0][kt], acc0b, 0,0,0);
      acc1b = __builtin_amdgcn_mfma_f32_16x16x32_bf16(a[kt], B[1][kt], acc1b, 0,0,0);
    } else {
      acc0a = __builtin_amdgcn_mfma_f32_16x16x32_bf16(a[kt], B[0][kt], acc0a, 0,0,0);
      acc1a = __builtin_amdgcn_mfma_f32_16x16x32_bf16(a[kt], B[1][kt], acc1a, 0,0,0);
    }
  }
  float h0[4], h1[4], s[4], q[4];
#pragma unroll
  for (int g=0; g<4; ++g){
    h0[g] = (acc0a[g]+acc0b[g]) + br[0];
    h1[g] = (acc1a[g]+acc1b[g]) + br[1];
    s[g] = h0[g] + h1[g];
    q[g] = h0[g]*h0[g] + h1[g]*h1[g];
  }
#pragma unroll
  for (int m=1; m<16; m<<=1){
#pragma unroll
    for (int g=0; g<4; ++g){
      s[g] += __shfl_xor(s[g], m, 64);
      q[g] += __shfl_xor(q[g], m, 64);
    }
  }
  if (lc == 0){
#pragma unroll
    for (int g=0; g<4; ++g)
      *(float2*)(part + (lg*4+g)*8 + w*2) = make_float2(s[g], q[g]);
  }
  lds_barrier();   // B1: partials visible
  // one row per lane, broadcast mu/rs to the 4 g-owners
  const int R = lg*4 + (lc & 3);
  f4 p0 = *(const f4*)(part + R*8);
  f4 p1 = *(const f4*)(part + R*8 + 4);
  float ss = (p0.x + p0.z) + (p1.x + p1.z);
  float qq = (p0.y + p0.w) + (p1.y + p1.w);
  float mu = ss * 0.0078125f;
  float rs = rsqrtf((qq * 0.0078125f - mu*mu) + EPS);
  const int c0 = w*32 + lc;
#pragma unroll
  for (int g=0; g<4; ++g){
    const float mug = __shfl(mu, (l & 48) | g, 64);
    const float rsg = __shfl(rs, (l & 48) | g, 64);
    const int row = lg*4 + g;
    float v0 = (h0[g]-mug)*rsg*gr[0] + ber[0];
    float v1 = (h1[g]-mug)*rsg*gr[1] + ber[1];
    actb[row*AS + c0]      = f2bf(tanh_fast(v0));
    actb[row*AS + c0 + 16] = f2bf(tanh_fast(v1));
  }
  lds_barrier();   // B2: act complete
}

__global__ __launch_bounds__(256, 1)
void latent_ode_v4(const float* __restrict__ z0, const float* __restrict__ tt,
                   const float* __restrict__ cond,
                   const float* __restrict__ W0, const float* __restrict__ b0,
                   const float* __restrict__ g0, const float* __restrict__ be0,
                   const float* __restrict__ W1, const float* __restrict__ b1,
                   const float* __restrict__ g1, const float* __restrict__ be1,
                   const float* __restrict__ W2, const float* __restrict__ b2,
                   const float* __restrict__ g2, const float* __restrict__ be2,
                   const float* __restrict__ Wo, const float* __restrict__ bo,
                   float* __restrict__ out)
{
  // xin K layout: [0:64 z_hi][64:128 z_lo][128:224 cond_hi][224:320 cond_lo]
  __shared__ __align__(16) unsigned short xin[16*XS];
  __shared__ __align__(16) unsigned short act[16*AS];
  __shared__ __align__(16) float dts[16*TS];
  __shared__ __align__(16) float part[16*8];

  const int t  = threadIdx.x;
  const int w  = t >> 6;
  const int l  = t & 63;
  const int lg = l >> 4;
  const int lc = l & 15;
  const int r0 = blockIdx.x * 16;
  const int colo = w*16 + lc;   // output-layer col owned by this lane

  // ---- weights -> VGPR B-fragments (one-time)
  bfrag B0f[2][10], B1f[2][4], B2f[2][4], Bof[4];
#pragma unroll
  for (int nt=0; nt<2; ++nt){
    const int col = w*32 + nt*16 + lc;
#pragma unroll
    for (int kt=0; kt<10; ++kt){
      union { bfrag v; unsigned short u[8]; } r;
#pragma unroll
      for (int j=0; j<8; ++j){
        const int k = kt*32 + lg*8 + j;
        const int src = (k<64) ? k : (k<128) ? (k-64) : (k<224) ? (64 + k-128) : (64 + k-224);
        r.u[j] = f2bf(W0[(size_t)src*128 + col]);
      }
      B0f[nt][kt] = r.v;
    }
#pragma unroll
    for (int kt=0; kt<4; ++kt){
      union { bfrag v; unsigned short u[8]; } r1, r2;
#pragma unroll
      for (int j=0; j<8; ++j){
        const int k = kt*32 + lg*8 + j;
        r1.u[j] = f2bf(W1[(size_t)k*128 + col]);
        r2.u[j] = f2bf(W2[(size_t)k*128 + col]);
      }
      B1f[nt][kt] = r1.v; B2f[nt][kt] = r2.v;
    }
  }
#pragma unroll
  for (int kt=0; kt<4; ++kt){
    union { bfrag v; unsigned short u[8]; } r;
#pragma unroll
    for (int j=0; j<8; ++j){
      const int k = kt*32 + lg*8 + j;
      r.u[j] = f2bf(Wo[(size_t)k*64 + colo]);
    }
    Bof[kt] = r.v;
  }
  float br0[2],gr0[2],ber0[2], br1[2],gr1[2],ber1[2], br2[2],gr2[2],ber2[2];
#pragma unroll
  for (int nt=0; nt<2; ++nt){
    const int col = w*32 + nt*16 + lc;
    br0[nt]=b0[col]; gr0[nt]=g0[col]; ber0[nt]=be0[col];
    br1[nt]=b1[col]; gr1[nt]=g1[col]; ber1[nt]=be1[col];
    br2[nt]=b2[col]; gr2[nt]=g2[col]; ber2[nt]=be2[col];
  }
  const float bor = bo[colo];

  // ---- dt table
  {
    const int row = t >> 4, j0 = t & 15;
    const float* tp = tt + (size_t)(r0+row)*NSEQ;
    for (int j=j0; j<NSEQ-1; j+=16)
      dts[row*TS + j] = tp[j+1] - tp[j];
  }

  // ---- z state in VGPRs (rows 4*lg+g, col colo) + xin z init + out step 0
  float zr[4];
#pragma unroll
  for (int g=0; g<4; ++g){
    const int row = lg*4 + g;
    const float z = z0[(size_t)(r0+row)*64 + colo];
    zr[g] = z;
    const unsigned short h = f2bf(z);
    xin[row*XS + colo]      = h;
    xin[row*XS + 64 + colo] = f2bf(z - bf2f(h));
    out[((size_t)(r0+row)*NSEQ)*64 + colo] = z;
  }

  // ---- cond: stage step 0 directly, prefetch step 1
  const int srow = t >> 4, sq = t & 15;   // 16 threads/row, float2 slots sq,sq+16,sq+32
  const float* cbase = cond + ((size_t)(r0+srow)*NSEQ)*96;
  float2 pf[3];
#pragma unroll
  for (int k2=0; k2<3; ++k2){
    const int s2 = (sq + 16*k2)*2;
    float2 c = *(const float2*)(cbase + s2);
    unsigned short h0 = f2bf(c.x), h1 = f2bf(c.y);
    *(uint32_t*)(xin + srow*XS + 128 + s2) = (uint32_t)h0 | ((uint32_t)h1 << 16);
    *(uint32_t*)(xin + srow*XS + 224 + s2) =
        (uint32_t)f2bf(c.x - bf2f(h0)) | ((uint32_t)f2bf(c.y - bf2f(h1)) << 16);
    pf[k2] = *(const float2*)(cbase + 96 + s2);
  }
  lds_barrier();

  for (int i=0; i<NSEQ-1; ++i){
    // prefetch dt early (used ~2500 cyc later at Lo)
    float dtv[4];
#pragma unroll
    for (int g=0; g<4; ++g) dtv[g] = dts[(lg*4+g)*TS + i];

    mlp_layer<10>(xin, XS, B0f, br0, gr0, ber0, act, part, w, l, lg, lc);
    mlp_layer<4> (act, AS, B1f, br1, gr1, ber1, act, part, w, l, lg, lc);
    mlp_layer<4> (act, AS, B2f, br2, gr2, ber2, act, part, w, l, lg, lc);

    // ---- output layer + Euler update (all waves symmetric: 16 cols each)
    {
      const int aoff = lc*AS + lg*8;
      bfrag a[4];
#pragma unroll
      for (int kt=0; kt<4; ++kt) a[kt] = *(const bfrag*)(act + aoff + kt*32);
      f4 aoa = {0,0,0,0}, aob = {0,0,0,0};
      aoa = __builtin_amdgcn_mfma_f32_16x16x32_bf16(a[0], Bof[0], aoa, 0,0,0);
      aob = __builtin_amdgcn_mfma_f32_16x16x32_bf16(a[1], Bof[1], aob, 0,0,0);
      aoa = __builtin_amdgcn_mfma_f32_16x16x32_bf16(a[2], Bof[2], aoa, 0,0,0);
      aob = __builtin_amdgcn_mfma_f32_16x16x32_bf16(a[3], Bof[3], aob, 0,0,0);
#pragma unroll
      for (int g=0; g<4; ++g){
        const int row = lg*4 + g;
        const float zn = zr[g] + dtv[g]*((aoa[g]+aob[g]) + bor);
        zr[g] = zn;
        out[((size_t)(r0+row)*NSEQ + (size_t)(i+1))*64 + colo] = zn;  // fire-and-forget
        const unsigned short h = f2bf(zn);
        xin[row*XS + colo]      = h;
        xin[row*XS + 64 + colo] = f2bf(zn - bf2f(h));
      }
    }

    // ---- stage cond(i+1) from prefetch regs; issue load of cond(i+2)
#pragma unroll
    for (int k2=0; k2<3; ++k2){
      const int s2 = (sq + 16*k2)*2;
      unsigned short h0 = f2bf(pf[k2].x), h1 = f2bf(pf[k2].y);
      *(uint32_t*)(xin + srow*XS + 128 + s2) = (uint32_t)h0 | ((uint32_t)h1 << 16);
      *(uint32_t*)(xin + srow*XS + 224 + s2) =
          (uint32_t)f2bf(pf[k2].x - bf2f(h0)) | ((uint32_t)f2bf(pf[k2].y - bf2f(h1)) << 16);
    }
    if (i < NSEQ-2){
#pragma unroll
      for (int k2=0; k2<3; ++k2)
        pf[k2] = *(const float2*)(cbase + (size_t)(i+2)*96 + (sq + 16*k2)*2);
    }
    lds_barrier();   // xin (z + cond for step i+1) ready
  }
}

extern "C" void kernel_launch(void* const* d_in, const int* in_sizes, int n_in,
                              void* d_out, int out_size, void* d_ws, size_t ws_size,
                              hipStream_t stream) {
  const float* z0   = (const float*)d_in[0];
  const float* tt   = (const float*)d_in[1];
  const float* cond = (const float*)d_in[2];
  const float* W0   = (const float*)d_in[3];
  const float* b0   = (const float*)d_in[4];
  const float* g0   = (const float*)d_in[5];
  const float* be0  = (const float*)d_in[6];
  const float* W1   = (const float*)d_in[7];
  const float* b1   = (const float*)d_in[8];
  const float* g1   = (const float*)d_in[9];
  const float* be1  = (const float*)d_in[10];
  const float* W2   = (const float*)d_in[11];
  const float* b2   = (const float*)d_in[12];
  const float* g2   = (const float*)d_in[13];
  const float* be2  = (const float*)d_in[14];
  const float* Wo   = (const float*)d_in[15];
  const float* bo   = (const float*)d_in[16];
  float* out = (float*)d_out;

  hipLaunchKernelGGL(latent_ode_v4, dim3(64), dim3(256), 0, stream,
                     z0, tt, cond, W0, b0, g0, be0, W1, b1, g1, be1,
                     W2, b2, g2, be2, Wo, bo, out);
}

// Round 5
// 1430.147 us; speedup vs baseline: 1.5281x; 1.5281x over previous
//
#include <hip/hip_runtime.h>
#include <stdint.h>

#define NSEQ 512
#define XS 328   // xin row stride (shorts): [0:64 z_hi][64:128 z_lo][128:224 c_hi][224:320 c_lo]
#define AS 136   // act row stride (shorts)
#define TS 516   // dts row stride (f32)
#define PS 36    // part row stride (f32): 16 (s,q) pairs + pad, 144B (16B-mult)
#define EPS 1e-5f

typedef short bfrag __attribute__((ext_vector_type(8)));
typedef float f4 __attribute__((ext_vector_type(4)));

__device__ __forceinline__ float lo16f(uint32_t u){ return __uint_as_float(u<<16); }
__device__ __forceinline__ float hi16f(uint32_t u){ return __uint_as_float(u & 0xFFFF0000u); }
__device__ __forceinline__ unsigned short f2bf(float f){
  uint32_t u = __float_as_uint(f);
  u += 0x7FFFu + ((u>>16)&1u);   // RNE
  return (unsigned short)(u>>16);
}
// packed f32x2 -> bf16x2 (RNE), low half = a, high half = b
__device__ __forceinline__ uint32_t pk2bf(float a, float b){
  uint32_t r;
  asm("v_cvt_pk_bf16_f32 %0, %1, %2" : "=v"(r) : "v"(a), "v"(b));
  return r;
}
__device__ __forceinline__ float tanh_fast(float v){
  float e = __builtin_amdgcn_exp2f(v * 2.8853900817779268f);  // e^(2v)
  float r = __builtin_amdgcn_rcpf(e + 1.f);
  return fmaf(-2.f, r, 1.f);
}
// LDS-only barrier: cross-lane data flows only through LDS; global prefetch
// loads (consumed by issuing thread; compiler inserts vmcnt) stay in flight.
__device__ __forceinline__ void lds_barrier(){
  asm volatile("s_waitcnt lgkmcnt(0)" ::: "memory");
  __builtin_amdgcn_s_barrier();
  asm volatile("" ::: "memory");
}

// Hidden layer, swapped operands: D[neuron][batch] = W^T-tile x x-tile.
// Lane: batch=lc, neurons {w*32+lg*4+g} and {w*32+16+lg*4+g}. Zero shuffles.
template<int NKT>
__device__ __forceinline__ void mlp_layer(
    const unsigned short* __restrict__ inb, const int istride,
    const bfrag (&A)[2][NKT],
    const float (&bd)[2][4], const float (&gd)[2][4], const float (&bed)[2][4],
    unsigned short* __restrict__ actb, float* __restrict__ part,
    const int w, const int lg, const int lc)
{
  const int boff = lc*istride + lg*8;
  bfrag b[NKT];
#pragma unroll
  for (int kt=0; kt<NKT; ++kt) b[kt] = *(const bfrag*)(inb + boff + kt*32);
  const f4 z4 = {0,0,0,0};
  f4 a0a=z4, a0b=z4, a1a=z4, a1b=z4;   // even/odd kt chains per m-tile
#pragma unroll
  for (int kt=0; kt<NKT; ++kt){
    if (kt&1){
      a0b = __builtin_amdgcn_mfma_f32_16x16x32_bf16(A[0][kt], b[kt], a0b,0,0,0);
      a1b = __builtin_amdgcn_mfma_f32_16x16x32_bf16(A[1][kt], b[kt], a1b,0,0,0);
    } else {
      a0a = __builtin_amdgcn_mfma_f32_16x16x32_bf16(A[0][kt], b[kt], a0a,0,0,0);
      a1a = __builtin_amdgcn_mfma_f32_16x16x32_bf16(A[1][kt], b[kt], a1a,0,0,0);
    }
  }
  float h0[4], h1[4];
#pragma unroll
  for (int g=0; g<4; ++g){
    h0[g] = (a0a[g]+a0b[g]) + bd[0][g];
    h1[g] = (a1a[g]+a1b[g]) + bd[1][g];
  }
  const float s = ((h0[0]+h0[1])+(h0[2]+h0[3])) + ((h1[0]+h1[1])+(h1[2]+h1[3]));
  const float q = (fmaf(h0[0],h0[0], h0[1]*h0[1]) + fmaf(h0[2],h0[2], h0[3]*h0[3]))
                + (fmaf(h1[0],h1[0], h1[1]*h1[1]) + fmaf(h1[2],h1[2], h1[3]*h1[3]));
  *(float2*)(part + lc*PS + (w*4+lg)*2) = make_float2(s, q);
  lds_barrier();   // B1: partials visible
  const float* pr = part + lc*PS;
  const f4 p0=*(const f4*)(pr),    p1=*(const f4*)(pr+4),  p2=*(const f4*)(pr+8),  p3=*(const f4*)(pr+12);
  const f4 p4=*(const f4*)(pr+16), p5=*(const f4*)(pr+20), p6=*(const f4*)(pr+24), p7=*(const f4*)(pr+28);
  const float ss = (((p0.x+p0.z)+(p1.x+p1.z)) + ((p2.x+p2.z)+(p3.x+p3.z)))
                 + (((p4.x+p4.z)+(p5.x+p5.z)) + ((p6.x+p6.z)+(p7.x+p7.z)));
  const float qq = (((p0.y+p0.w)+(p1.y+p1.w)) + ((p2.y+p2.w)+(p3.y+p3.w)))
                 + (((p4.y+p4.w)+(p5.y+p5.w)) + ((p6.y+p6.w)+(p7.y+p7.w)));
  const float mu = ss * 0.0078125f;
  const float rs = rsqrtf(fmaf(qq, 0.0078125f, -mu*mu) + EPS);
  float e0[4], e1[4];
#pragma unroll
  for (int g=0; g<4; ++g){
    e0[g] = tanh_fast(fmaf((h0[g]-mu)*rs, gd[0][g], bed[0][g]));
    e1[g] = tanh_fast(fmaf((h1[g]-mu)*rs, gd[1][g], bed[1][g]));
  }
  const int abase = lc*AS + w*32 + lg*4;
  *(uint2*)(actb + abase)      = make_uint2(pk2bf(e0[0],e0[1]), pk2bf(e0[2],e0[3]));
  *(uint2*)(actb + abase + 16) = make_uint2(pk2bf(e1[0],e1[1]), pk2bf(e1[2],e1[3]));
  lds_barrier();   // B2: act complete
}

__global__ __launch_bounds__(256, 1)
void latent_ode_v5(const float* __restrict__ z0, const float* __restrict__ tt,
                   const float* __restrict__ cond,
                   const float* __restrict__ W0, const float* __restrict__ b0,
                   const float* __restrict__ g0, const float* __restrict__ be0,
                   const float* __restrict__ W1, const float* __restrict__ b1,
                   const float* __restrict__ g1, const float* __restrict__ be1,
                   const float* __restrict__ W2, const float* __restrict__ b2,
                   const float* __restrict__ g2, const float* __restrict__ be2,
                   const float* __restrict__ Wo, const float* __restrict__ bo,
                   float* __restrict__ out)
{
  __shared__ __align__(16) unsigned short xin[16*XS];
  __shared__ __align__(16) unsigned short act[16*AS];
  __shared__ __align__(16) float dts[16*TS];
  __shared__ __align__(16) float part[16*PS];

  const int t  = threadIdx.x;
  const int w  = t >> 6;
  const int l  = t & 63;
  const int lg = l >> 4;
  const int lc = l & 15;
  const int r0 = blockIdx.x * 16;

  // ---- weight fragments (A-role now; same lane layout as the old B-role)
  bfrag A0f[2][10], A1f[2][4], A2f[2][4], Aof[4];
#pragma unroll
  for (int nt=0; nt<2; ++nt){
    const int col = w*32 + nt*16 + lc;
#pragma unroll
    for (int kt=0; kt<10; ++kt){
      union { bfrag v; unsigned short u[8]; } r;
#pragma unroll
      for (int j=0; j<8; ++j){
        const int k = kt*32 + lg*8 + j;
        const int src = (k<64) ? k : (k<128) ? (k-64) : (k<224) ? (64 + k-128) : (64 + k-224);
        r.u[j] = f2bf(W0[(size_t)src*128 + col]);
      }
      A0f[nt][kt] = r.v;
    }
#pragma unroll
    for (int kt=0; kt<4; ++kt){
      union { bfrag v; unsigned short u[8]; } r1, r2;
#pragma unroll
      for (int j=0; j<8; ++j){
        const int k = kt*32 + lg*8 + j;
        r1.u[j] = f2bf(W1[(size_t)k*128 + col]);
        r2.u[j] = f2bf(W2[(size_t)k*128 + col]);
      }
      A1f[nt][kt] = r1.v; A2f[nt][kt] = r2.v;
    }
  }
  const int zcol = w*16 + lg*4;          // this lane's 4 output latents
#pragma unroll
  for (int kt=0; kt<4; ++kt){
    union { bfrag v; unsigned short u[8]; } r;
#pragma unroll
    for (int j=0; j<8; ++j){
      const int k = kt*32 + lg*8 + j;
      r.u[j] = f2bf(Wo[(size_t)k*64 + (w*16 + lc)]);
    }
    Aof[kt] = r.v;
  }
  // per-lane D-pattern params: neuron n = w*32 + nt*16 + lg*4 + g
  float bd0[2][4], gd0[2][4], bed0[2][4];
  float bd1[2][4], gd1[2][4], bed1[2][4];
  float bd2[2][4], gd2[2][4], bed2[2][4];
  float bo_d[4];
#pragma unroll
  for (int nt=0; nt<2; ++nt){
#pragma unroll
    for (int g=0; g<4; ++g){
      const int n = w*32 + nt*16 + lg*4 + g;
      bd0[nt][g]=b0[n]; gd0[nt][g]=g0[n]; bed0[nt][g]=be0[n];
      bd1[nt][g]=b1[n]; gd1[nt][g]=g1[n]; bed1[nt][g]=be1[n];
      bd2[nt][g]=b2[n]; gd2[nt][g]=g2[n]; bed2[nt][g]=be2[n];
    }
  }
#pragma unroll
  for (int g=0; g<4; ++g) bo_d[g] = bo[zcol + g];

  // ---- dt table
  {
    const int row = t >> 4, j0 = t & 15;
    const float* tp = tt + (size_t)(r0+row)*NSEQ;
    for (int j=j0; j<NSEQ-1; j+=16)
      dts[row*TS + j] = tp[j+1] - tp[j];
  }

  // ---- z state: lane holds z[batch lc][zcol..zcol+3]
  float zr0, zr1, zr2, zr3;
  {
    const f4 zv = *(const f4*)(z0 + (size_t)(r0+lc)*64 + zcol);
    zr0=zv[0]; zr1=zv[1]; zr2=zv[2]; zr3=zv[3];
    *(f4*)(out + ((size_t)(r0+lc)*NSEQ)*64 + zcol) = zv;
    const uint32_t u01 = pk2bf(zv[0],zv[1]), u23 = pk2bf(zv[2],zv[3]);
    const uint32_t l01 = pk2bf(zv[0]-lo16f(u01), zv[1]-hi16f(u01));
    const uint32_t l23 = pk2bf(zv[2]-lo16f(u23), zv[3]-hi16f(u23));
    *(uint2*)(xin + lc*XS + zcol)      = make_uint2(u01,u23);
    *(uint2*)(xin + lc*XS + 64 + zcol) = make_uint2(l01,l23);
  }

  // ---- cond: stage step 0, prefetch step 1
  const int srow = t >> 4, sq = t & 15;
  const float* cbase = cond + ((size_t)(r0+srow)*NSEQ)*96;
  float2 pf[3];
#pragma unroll
  for (int k2=0; k2<3; ++k2){
    const int s2 = (sq + 16*k2)*2;
    const float2 c = *(const float2*)(cbase + s2);
    const uint32_t uh = pk2bf(c.x, c.y);
    *(uint32_t*)(xin + srow*XS + 128 + s2) = uh;
    *(uint32_t*)(xin + srow*XS + 224 + s2) = pk2bf(c.x - lo16f(uh), c.y - hi16f(uh));
    pf[k2] = *(const float2*)(cbase + 96 + s2);
  }
  lds_barrier();

  for (int i=0; i<NSEQ-1; ++i){
    mlp_layer<10>(xin, XS, A0f, bd0, gd0, bed0, act, part, w, lg, lc);
    mlp_layer<4> (act, AS, A1f, bd1, gd1, bed1, act, part, w, lg, lc);
    mlp_layer<4> (act, AS, A2f, bd2, gd2, bed2, act, part, w, lg, lc);

    // ---- output layer (swapped): D[latent][batch]; lane: batch lc, latents zcol+g
    {
      const int boff = lc*AS + lg*8;
      bfrag b[4];
#pragma unroll
      for (int kt=0; kt<4; ++kt) b[kt] = *(const bfrag*)(act + boff + kt*32);
      f4 aa = {0,0,0,0}, ab = {0,0,0,0};
      aa = __builtin_amdgcn_mfma_f32_16x16x32_bf16(Aof[0], b[0], aa,0,0,0);
      ab = __builtin_amdgcn_mfma_f32_16x16x32_bf16(Aof[1], b[1], ab,0,0,0);
      aa = __builtin_amdgcn_mfma_f32_16x16x32_bf16(Aof[2], b[2], aa,0,0,0);
      ab = __builtin_amdgcn_mfma_f32_16x16x32_bf16(Aof[3], b[3], ab,0,0,0);
      const float dt = dts[lc*TS + i];
      f4 zn;
      zn[0] = fmaf(dt, (aa[0]+ab[0]) + bo_d[0], zr0);
      zn[1] = fmaf(dt, (aa[1]+ab[1]) + bo_d[1], zr1);
      zn[2] = fmaf(dt, (aa[2]+ab[2]) + bo_d[2], zr2);
      zn[3] = fmaf(dt, (aa[3]+ab[3]) + bo_d[3], zr3);
      zr0=zn[0]; zr1=zn[1]; zr2=zn[2]; zr3=zn[3];
      *(f4*)(out + ((size_t)(r0+lc)*NSEQ + (size_t)(i+1))*64 + zcol) = zn;  // coalesced-ish float4
      const uint32_t u01 = pk2bf(zn[0],zn[1]), u23 = pk2bf(zn[2],zn[3]);
      const uint32_t l01 = pk2bf(zn[0]-lo16f(u01), zn[1]-hi16f(u01));
      const uint32_t l23 = pk2bf(zn[2]-lo16f(u23), zn[3]-hi16f(u23));
      *(uint2*)(xin + lc*XS + zcol)      = make_uint2(u01,u23);
      *(uint2*)(xin + lc*XS + 64 + zcol) = make_uint2(l01,l23);
    }

    // ---- stage cond(i+1); issue load of cond(i+2)
#pragma unroll
    for (int k2=0; k2<3; ++k2){
      const int s2 = (sq + 16*k2)*2;
      const uint32_t uh = pk2bf(pf[k2].x, pf[k2].y);
      *(uint32_t*)(xin + srow*XS + 128 + s2) = uh;
      *(uint32_t*)(xin + srow*XS + 224 + s2) = pk2bf(pf[k2].x - lo16f(uh), pf[k2].y - hi16f(uh));
    }
    if (i < NSEQ-2){
#pragma unroll
      for (int k2=0; k2<3; ++k2)
        pf[k2] = *(const float2*)(cbase + (size_t)(i+2)*96 + (sq + 16*k2)*2);
    }
    lds_barrier();   // xin (z + cond for step i+1) ready
  }
}

extern "C" void kernel_launch(void* const* d_in, const int* in_sizes, int n_in,
                              void* d_out, int out_size, void* d_ws, size_t ws_size,
                              hipStream_t stream) {
  const float* z0   = (const float*)d_in[0];
  const float* tt   = (const float*)d_in[1];
  const float* cond = (const float*)d_in[2];
  const float* W0   = (const float*)d_in[3];
  const float* b0   = (const float*)d_in[4];
  const float* g0   = (const float*)d_in[5];
  const float* be0  = (const float*)d_in[6];
  const float* W1   = (const float*)d_in[7];
  const float* b1   = (const float*)d_in[8];
  const float* g1   = (const float*)d_in[9];
  const float* be1  = (const float*)d_in[10];
  const float* W2   = (const float*)d_in[11];
  const float* b2   = (const float*)d_in[12];
  const float* g2   = (const float*)d_in[13];
  const float* be2  = (const float*)d_in[14];
  const float* Wo   = (const float*)d_in[15];
  const float* bo   = (const float*)d_in[16];
  float* out = (float*)d_out;

  hipLaunchKernelGGL(latent_ode_v5, dim3(64), dim3(256), 0, stream,
                     z0, tt, cond, W0, b0, g0, be0, W1, b1, g1, be1,
                     W2, b2, g2, be2, Wo, bo, out);
}

// Round 6
// 1201.578 us; speedup vs baseline: 1.8188x; 1.1902x over previous
//
#include <hip/hip_runtime.h>
#include <stdint.h>

#define NSEQ 512
#define XS 328   // xin row stride (shorts): [0:64 z_hi][64:128 z_lo][128:224 c_hi][224:320 c_lo]
#define AS 136   // act row stride (shorts)
#define TS 516   // dts row stride (f32)
#define PS 36    // part row stride (f32)
#define EPS 1e-5f

typedef short bfrag __attribute__((ext_vector_type(8)));
typedef float f4 __attribute__((ext_vector_type(4)));

__device__ __forceinline__ float lo16f(uint32_t u){ return __uint_as_float(u<<16); }
__device__ __forceinline__ float hi16f(uint32_t u){ return __uint_as_float(u & 0xFFFF0000u); }
__device__ __forceinline__ unsigned short f2bf(float f){
  uint32_t u = __float_as_uint(f);
  u += 0x7FFFu + ((u>>16)&1u);   // RNE
  return (unsigned short)(u>>16);
}
__device__ __forceinline__ uint32_t pk2bf(float a, float b){
  uint32_t r;
  asm("v_cvt_pk_bf16_f32 %0, %1, %2" : "=v"(r) : "v"(a), "v"(b));
  return r;
}
__device__ __forceinline__ float tanh_fast(float v){
  float e = __builtin_amdgcn_exp2f(v * 2.8853900817779268f);  // e^(2v)
  float r = __builtin_amdgcn_rcpf(e + 1.f);
  return fmaf(-2.f, r, 1.f);
}
__device__ __forceinline__ void lds_barrier(){
  asm volatile("s_waitcnt lgkmcnt(0)" ::: "memory");
  __builtin_amdgcn_s_barrier();
  asm volatile("" ::: "memory");
}

// stats partial: s,q over this lane's 8 neurons -> part[batch][slot w*4+lg]
__device__ __forceinline__ void stats_write(const float (&h0)[4], const float (&h1)[4],
                                            float* __restrict__ part,
                                            const int w, const int lg, const int lc){
  const float s = ((h0[0]+h0[1])+(h0[2]+h0[3])) + ((h1[0]+h1[1])+(h1[2]+h1[3]));
  const float q = (fmaf(h0[0],h0[0], h0[1]*h0[1]) + fmaf(h0[2],h0[2], h0[3]*h0[3]))
                + (fmaf(h1[0],h1[0], h1[1]*h1[1]) + fmaf(h1[2],h1[2], h1[3]*h1[3]));
  *(float2*)(part + lc*PS + (w*4+lg)*2) = make_float2(s, q);
}

// LN + tanh + single-b128 act store (lane's 8 neurons are contiguous: w*32+lg*8+0..7)
__device__ __forceinline__ void ln_tanh_store(const float (&h0)[4], const float (&h1)[4],
                                              const float (&gd)[2][4], const float (&bed)[2][4],
                                              const float* __restrict__ part,
                                              unsigned short* __restrict__ actb,
                                              const int w, const int lg, const int lc){
  const float* pr = part + lc*PS;
  const f4 p0=*(const f4*)(pr),    p1=*(const f4*)(pr+4),  p2=*(const f4*)(pr+8),  p3=*(const f4*)(pr+12);
  const f4 p4=*(const f4*)(pr+16), p5=*(const f4*)(pr+20), p6=*(const f4*)(pr+24), p7=*(const f4*)(pr+28);
  const float ss = (((p0.x+p0.z)+(p1.x+p1.z)) + ((p2.x+p2.z)+(p3.x+p3.z)))
                 + (((p4.x+p4.z)+(p5.x+p5.z)) + ((p6.x+p6.z)+(p7.x+p7.z)));
  const float qq = (((p0.y+p0.w)+(p1.y+p1.w)) + ((p2.y+p2.w)+(p3.y+p3.w)))
                 + (((p4.y+p4.w)+(p5.y+p5.w)) + ((p6.y+p6.w)+(p7.y+p7.w)));
  const float mu = ss * 0.0078125f;
  const float rs = rsqrtf(fmaf(qq, 0.0078125f, -mu*mu) + EPS);
  float e0[4], e1[4];
#pragma unroll
  for (int g=0; g<4; ++g){
    e0[g] = tanh_fast(fmaf((h0[g]-mu)*rs, gd[0][g], bed[0][g]));
    e1[g] = tanh_fast(fmaf((h1[g]-mu)*rs, gd[1][g], bed[1][g]));
  }
  uint4 pk4;
  pk4.x = pk2bf(e0[0],e0[1]); pk4.y = pk2bf(e0[2],e0[3]);
  pk4.z = pk2bf(e1[0],e1[1]); pk4.w = pk2bf(e1[2],e1[3]);
  *(uint4*)(actb + lc*AS + w*32 + lg*8) = pk4;
}

__global__ __launch_bounds__(256, 1)
void latent_ode_v6(const float* __restrict__ z0, const float* __restrict__ tt,
                   const float* __restrict__ cond,
                   const float* __restrict__ W0, const float* __restrict__ b0,
                   const float* __restrict__ g0, const float* __restrict__ be0,
                   const float* __restrict__ W1, const float* __restrict__ b1,
                   const float* __restrict__ g1, const float* __restrict__ be1,
                   const float* __restrict__ W2, const float* __restrict__ b2,
                   const float* __restrict__ g2, const float* __restrict__ be2,
                   const float* __restrict__ Wo, const float* __restrict__ bo,
                   float* __restrict__ out)
{
  __shared__ __align__(16) unsigned short xin[16*XS];
  __shared__ __align__(16) unsigned short act[16*AS];
  __shared__ __align__(16) float dts[16*TS];
  __shared__ __align__(16) float part[16*PS];

  const int t  = threadIdx.x;
  const int w  = t >> 6;
  const int l  = t & 63;
  const int lg = l >> 4;
  const int lc = l & 15;
  const int r0 = blockIdx.x * 16;
  const int zcol = w*16 + lg*4;

  // ---- weight fragments. Hidden-tile row permutation r -> (r>>2)*8 + (r&3):
  // lane's D rows (4lg+g) of tiles nt=0,1 map to neurons w*32+lg*8+nt*4+g -> 8 contiguous.
  bfrag A0z[2][4], A0c[2][6], A1f[2][4], A2f[2][4], Aof[4];
#pragma unroll
  for (int nt=0; nt<2; ++nt){
    const int col = w*32 + nt*4 + ((lc>>2)<<3) + (lc&3);
#pragma unroll
    for (int kt=0; kt<4; ++kt){   // z hi (kt0,1) / z lo (kt2,3): same W rows 0..63
      union { bfrag v; unsigned short u[8]; } r;
#pragma unroll
      for (int j=0; j<8; ++j)
        r.u[j] = f2bf(W0[(size_t)((kt&1)*32 + lg*8 + j)*128 + col]);
      A0z[nt][kt] = r.v;
    }
#pragma unroll
    for (int s=0; s<6; ++s){      // cond hi (0..2) / lo (3..5): W rows 64..159
      const int sm = (s<3)? s : s-3;
      union { bfrag v; unsigned short u[8]; } r;
#pragma unroll
      for (int j=0; j<8; ++j)
        r.u[j] = f2bf(W0[(size_t)(64 + sm*32 + lg*8 + j)*128 + col]);
      A0c[nt][s] = r.v;
    }
#pragma unroll
    for (int kt=0; kt<4; ++kt){
      union { bfrag v; unsigned short u[8]; } r1, r2;
#pragma unroll
      for (int j=0; j<8; ++j){
        const int k = kt*32 + lg*8 + j;
        r1.u[j] = f2bf(W1[(size_t)k*128 + col]);
        r2.u[j] = f2bf(W2[(size_t)k*128 + col]);
      }
      A1f[nt][kt] = r1.v; A2f[nt][kt] = r2.v;
    }
  }
#pragma unroll
  for (int kt=0; kt<4; ++kt){     // output tile: identity row map, col = w*16+lc
    union { bfrag v; unsigned short u[8]; } r;
#pragma unroll
    for (int j=0; j<8; ++j)
      r.u[j] = f2bf(Wo[(size_t)(kt*32 + lg*8 + j)*64 + (w*16 + lc)]);
    Aof[kt] = r.v;
  }
  float bd0[2][4], gd0[2][4], bed0[2][4];
  float bd1[2][4], gd1[2][4], bed1[2][4];
  float bd2[2][4], gd2[2][4], bed2[2][4];
  float bo_d[4];
#pragma unroll
  for (int nt=0; nt<2; ++nt){
#pragma unroll
    for (int g=0; g<4; ++g){
      const int n = w*32 + lg*8 + nt*4 + g;
      bd0[nt][g]=b0[n]; gd0[nt][g]=g0[n]; bed0[nt][g]=be0[n];
      bd1[nt][g]=b1[n]; gd1[nt][g]=g1[n]; bed1[nt][g]=be1[n];
      bd2[nt][g]=b2[n]; gd2[nt][g]=g2[n]; bed2[nt][g]=be2[n];
    }
  }
#pragma unroll
  for (int g=0; g<4; ++g) bo_d[g] = bo[zcol + g];

  // ---- dt table
  {
    const int row = t >> 4, j0 = t & 15;
    const float* tp = tt + (size_t)(r0+row)*NSEQ;
    for (int j=j0; j<NSEQ-1; j+=16)
      dts[row*TS + j] = tp[j+1] - tp[j];
  }

  // ---- z state: lane holds z[batch lc][zcol..zcol+3]
  f4 zr;
  {
    const f4 zv = *(const f4*)(z0 + (size_t)(r0+lc)*64 + zcol);
    zr = zv;
    *(f4*)(out + ((size_t)(r0+lc)*NSEQ)*64 + zcol) = zv;
    const uint32_t u01 = pk2bf(zv[0],zv[1]), u23 = pk2bf(zv[2],zv[3]);
    const uint32_t l01 = pk2bf(zv[0]-lo16f(u01), zv[1]-hi16f(u01));
    const uint32_t l23 = pk2bf(zv[2]-lo16f(u23), zv[3]-hi16f(u23));
    *(uint2*)(xin + lc*XS + zcol)      = make_uint2(u01,u23);
    *(uint2*)(xin + lc*XS + 64 + zcol) = make_uint2(l01,l23);
  }

  // ---- cond(0) staged, pf = cond(1)
  const int srow = t >> 4, sq = t & 15;
  const float* cbase = cond + ((size_t)(r0+srow)*NSEQ)*96;
  float2 pf[3];
#pragma unroll
  for (int k2=0; k2<3; ++k2){
    const int s2 = (sq + 16*k2)*2;
    const float2 c = *(const float2*)(cbase + s2);
    const uint32_t uh = pk2bf(c.x, c.y);
    *(uint32_t*)(xin + srow*XS + 128 + s2) = uh;
    *(uint32_t*)(xin + srow*XS + 224 + s2) = pk2bf(c.x - lo16f(uh), c.y - hi16f(uh));
    pf[k2] = *(const float2*)(cbase + 96 + s2);
  }
  lds_barrier();

  // ---- prologue pre-acc of cond(0)
  f4 apC[2], apE[2];
  {
    bfrag bc[6];
#pragma unroll
    for (int s=0; s<6; ++s){
      const int off = lc*XS + ((s<3)? (128 + s*32) : (224 + (s-3)*32)) + lg*8;
      bc[s] = *(const bfrag*)(xin + off);
    }
#pragma unroll
    for (int nt=0; nt<2; ++nt){
      f4 a = {0,0,0,0}, b = {0,0,0,0};
      a = __builtin_amdgcn_mfma_f32_16x16x32_bf16(A0c[nt][0], bc[0], a,0,0,0);
      a = __builtin_amdgcn_mfma_f32_16x16x32_bf16(A0c[nt][1], bc[1], a,0,0,0);
      a = __builtin_amdgcn_mfma_f32_16x16x32_bf16(A0c[nt][2], bc[2], a,0,0,0);
      b = __builtin_amdgcn_mfma_f32_16x16x32_bf16(A0c[nt][3], bc[3], b,0,0,0);
      b = __builtin_amdgcn_mfma_f32_16x16x32_bf16(A0c[nt][4], bc[4], b,0,0,0);
      b = __builtin_amdgcn_mfma_f32_16x16x32_bf16(A0c[nt][5], bc[5], b,0,0,0);
      if (nt==0){ apC[0]=a; apE[0]=b; } else { apC[1]=a; apE[1]=b; }
    }
  }

  float dtv = 0.f;
  for (int i=0; i<NSEQ-1; ++i){
    float h0[4], h1[4];
    // ---- S_A: L0 z-part MFMAs + combine with pre-acc; stats; cond(i+1) staging
    {
      bfrag bz[4];
      const int zoff = lc*XS + lg*8;
#pragma unroll
      for (int kt=0; kt<4; ++kt) bz[kt] = *(const bfrag*)(xin + zoff + kt*32);
      f4 c0a={0,0,0,0}, c0b={0,0,0,0}, c1a={0,0,0,0}, c1b={0,0,0,0};
      c0a = __builtin_amdgcn_mfma_f32_16x16x32_bf16(A0z[0][0], bz[0], c0a,0,0,0);
      c0b = __builtin_amdgcn_mfma_f32_16x16x32_bf16(A0z[0][1], bz[1], c0b,0,0,0);
      c1a = __builtin_amdgcn_mfma_f32_16x16x32_bf16(A0z[1][0], bz[0], c1a,0,0,0);
      c1b = __builtin_amdgcn_mfma_f32_16x16x32_bf16(A0z[1][1], bz[1], c1b,0,0,0);
      c0a = __builtin_amdgcn_mfma_f32_16x16x32_bf16(A0z[0][2], bz[2], c0a,0,0,0);
      c0b = __builtin_amdgcn_mfma_f32_16x16x32_bf16(A0z[0][3], bz[3], c0b,0,0,0);
      c1a = __builtin_amdgcn_mfma_f32_16x16x32_bf16(A0z[1][2], bz[2], c1a,0,0,0);
      c1b = __builtin_amdgcn_mfma_f32_16x16x32_bf16(A0z[1][3], bz[3], c1b,0,0,0);
#pragma unroll
      for (int g=0; g<4; ++g){
        h0[g] = ((c0a[g]+c0b[g]) + (apC[0][g]+apE[0][g])) + bd0[0][g];
        h1[g] = ((c1a[g]+c1b[g]) + (apC[1][g]+apE[1][g])) + bd0[1][g];
      }
      stats_write(h0, h1, part, w, lg, lc);
    }
#pragma unroll
    for (int k2=0; k2<3; ++k2){
      const int s2 = (sq + 16*k2)*2;
      const uint32_t uh = pk2bf(pf[k2].x, pf[k2].y);
      *(uint32_t*)(xin + srow*XS + 128 + s2) = uh;
      *(uint32_t*)(xin + srow*XS + 224 + s2) = pk2bf(pf[k2].x - lo16f(uh), pf[k2].y - hi16f(uh));
    }
    if (i < NSEQ-2){
#pragma unroll
      for (int k2=0; k2<3; ++k2)
        pf[k2] = *(const float2*)(cbase + (size_t)(i+2)*96 + (sq + 16*k2)*2);
    }
    lds_barrier();

    // ---- S_B: LN0 (+ background pre-acc slots 0..2 of cond(i+1))
    {
      bfrag bc0, bc1, bc2;
      bc0 = *(const bfrag*)(xin + lc*XS + 128      + lg*8);
      bc1 = *(const bfrag*)(xin + lc*XS + 128 + 32 + lg*8);
      bc2 = *(const bfrag*)(xin + lc*XS + 128 + 64 + lg*8);
      f4 a0={0,0,0,0}, a1={0,0,0,0};
      a0 = __builtin_amdgcn_mfma_f32_16x16x32_bf16(A0c[0][0], bc0, a0,0,0,0);
      a1 = __builtin_amdgcn_mfma_f32_16x16x32_bf16(A0c[1][0], bc0, a1,0,0,0);
      a0 = __builtin_amdgcn_mfma_f32_16x16x32_bf16(A0c[0][1], bc1, a0,0,0,0);
      a1 = __builtin_amdgcn_mfma_f32_16x16x32_bf16(A0c[1][1], bc1, a1,0,0,0);
      a0 = __builtin_amdgcn_mfma_f32_16x16x32_bf16(A0c[0][2], bc2, a0,0,0,0);
      a1 = __builtin_amdgcn_mfma_f32_16x16x32_bf16(A0c[1][2], bc2, a1,0,0,0);
      ln_tanh_store(h0, h1, gd0, bed0, part, act, w, lg, lc);
      apC[0]=a0; apC[1]=a1;
    }
    lds_barrier();

    // ---- S_C: L1
    {
      bfrag ba[4];
      const int aoff = lc*AS + lg*8;
#pragma unroll
      for (int kt=0; kt<4; ++kt) ba[kt] = *(const bfrag*)(act + aoff + kt*32);
      f4 c0a={0,0,0,0}, c0b={0,0,0,0}, c1a={0,0,0,0}, c1b={0,0,0,0};
      c0a = __builtin_amdgcn_mfma_f32_16x16x32_bf16(A1f[0][0], ba[0], c0a,0,0,0);
      c0b = __builtin_amdgcn_mfma_f32_16x16x32_bf16(A1f[0][1], ba[1], c0b,0,0,0);
      c1a = __builtin_amdgcn_mfma_f32_16x16x32_bf16(A1f[1][0], ba[0], c1a,0,0,0);
      c1b = __builtin_amdgcn_mfma_f32_16x16x32_bf16(A1f[1][1], ba[1], c1b,0,0,0);
      c0a = __builtin_amdgcn_mfma_f32_16x16x32_bf16(A1f[0][2], ba[2], c0a,0,0,0);
      c0b = __builtin_amdgcn_mfma_f32_16x16x32_bf16(A1f[0][3], ba[3], c0b,0,0,0);
      c1a = __builtin_amdgcn_mfma_f32_16x16x32_bf16(A1f[1][2], ba[2], c1a,0,0,0);
      c1b = __builtin_amdgcn_mfma_f32_16x16x32_bf16(A1f[1][3], ba[3], c1b,0,0,0);
#pragma unroll
      for (int g=0; g<4; ++g){
        h0[g] = (c0a[g]+c0b[g]) + bd1[0][g];
        h1[g] = (c1a[g]+c1b[g]) + bd1[1][g];
      }
      stats_write(h0, h1, part, w, lg, lc);
    }
    lds_barrier();

    // ---- S_D: LN1 (+ background pre-acc slots 3..5)
    {
      bfrag bc3, bc4, bc5;
      bc3 = *(const bfrag*)(xin + lc*XS + 224      + lg*8);
      bc4 = *(const bfrag*)(xin + lc*XS + 224 + 32 + lg*8);
      bc5 = *(const bfrag*)(xin + lc*XS + 224 + 64 + lg*8);
      f4 a0={0,0,0,0}, a1={0,0,0,0};
      a0 = __builtin_amdgcn_mfma_f32_16x16x32_bf16(A0c[0][3], bc3, a0,0,0,0);
      a1 = __builtin_amdgcn_mfma_f32_16x16x32_bf16(A0c[1][3], bc3, a1,0,0,0);
      a0 = __builtin_amdgcn_mfma_f32_16x16x32_bf16(A0c[0][4], bc4, a0,0,0,0);
      a1 = __builtin_amdgcn_mfma_f32_16x16x32_bf16(A0c[1][4], bc4, a1,0,0,0);
      a0 = __builtin_amdgcn_mfma_f32_16x16x32_bf16(A0c[0][5], bc5, a0,0,0,0);
      a1 = __builtin_amdgcn_mfma_f32_16x16x32_bf16(A0c[1][5], bc5, a1,0,0,0);
      ln_tanh_store(h0, h1, gd1, bed1, part, act, w, lg, lc);
      apE[0]=a0; apE[1]=a1;
    }
    lds_barrier();

    // ---- S_E: L2 (+ dt prefetch)
    {
      bfrag ba[4];
      const int aoff = lc*AS + lg*8;
#pragma unroll
      for (int kt=0; kt<4; ++kt) ba[kt] = *(const bfrag*)(act + aoff + kt*32);
      dtv = dts[lc*TS + i];
      f4 c0a={0,0,0,0}, c0b={0,0,0,0}, c1a={0,0,0,0}, c1b={0,0,0,0};
      c0a = __builtin_amdgcn_mfma_f32_16x16x32_bf16(A2f[0][0], ba[0], c0a,0,0,0);
      c0b = __builtin_amdgcn_mfma_f32_16x16x32_bf16(A2f[0][1], ba[1], c0b,0,0,0);
      c1a = __builtin_amdgcn_mfma_f32_16x16x32_bf16(A2f[1][0], ba[0], c1a,0,0,0);
      c1b = __builtin_amdgcn_mfma_f32_16x16x32_bf16(A2f[1][1], ba[1], c1b,0,0,0);
      c0a = __builtin_amdgcn_mfma_f32_16x16x32_bf16(A2f[0][2], ba[2], c0a,0,0,0);
      c0b = __builtin_amdgcn_mfma_f32_16x16x32_bf16(A2f[0][3], ba[3], c0b,0,0,0);
      c1a = __builtin_amdgcn_mfma_f32_16x16x32_bf16(A2f[1][2], ba[2], c1a,0,0,0);
      c1b = __builtin_amdgcn_mfma_f32_16x16x32_bf16(A2f[1][3], ba[3], c1b,0,0,0);
#pragma unroll
      for (int g=0; g<4; ++g){
        h0[g] = (c0a[g]+c0b[g]) + bd2[0][g];
        h1[g] = (c1a[g]+c1b[g]) + bd2[1][g];
      }
      stats_write(h0, h1, part, w, lg, lc);
    }
    lds_barrier();

    // ---- S_F: LN2
    ln_tanh_store(h0, h1, gd2, bed2, part, act, w, lg, lc);
    lds_barrier();

    // ---- S_G: output layer + Euler + stores
    {
      bfrag ba[4];
      const int aoff = lc*AS + lg*8;
#pragma unroll
      for (int kt=0; kt<4; ++kt) ba[kt] = *(const bfrag*)(act + aoff + kt*32);
      f4 aa={0,0,0,0}, ab={0,0,0,0};
      aa = __builtin_amdgcn_mfma_f32_16x16x32_bf16(Aof[0], ba[0], aa,0,0,0);
      ab = __builtin_amdgcn_mfma_f32_16x16x32_bf16(Aof[1], ba[1], ab,0,0,0);
      aa = __builtin_amdgcn_mfma_f32_16x16x32_bf16(Aof[2], ba[2], aa,0,0,0);
      ab = __builtin_amdgcn_mfma_f32_16x16x32_bf16(Aof[3], ba[3], ab,0,0,0);
      f4 zn;
#pragma unroll
      for (int g=0; g<4; ++g) zn[g] = fmaf(dtv, (aa[g]+ab[g]) + bo_d[g], zr[g]);
      zr = zn;
      *(f4*)(out + ((size_t)(r0+lc)*NSEQ + (size_t)(i+1))*64 + zcol) = zn;
      const uint32_t u01 = pk2bf(zn[0],zn[1]), u23 = pk2bf(zn[2],zn[3]);
      const uint32_t l01 = pk2bf(zn[0]-lo16f(u01), zn[1]-hi16f(u01));
      const uint32_t l23 = pk2bf(zn[2]-lo16f(u23), zn[3]-hi16f(u23));
      *(uint2*)(xin + lc*XS + zcol)      = make_uint2(u01,u23);
      *(uint2*)(xin + lc*XS + 64 + zcol) = make_uint2(l01,l23);
    }
    lds_barrier();
  }
}

extern "C" void kernel_launch(void* const* d_in, const int* in_sizes, int n_in,
                              void* d_out, int out_size, void* d_ws, size_t ws_size,
                              hipStream_t stream) {
  const float* z0   = (const float*)d_in[0];
  const float* tt   = (const float*)d_in[1];
  const float* cond = (const float*)d_in[2];
  const float* W0   = (const float*)d_in[3];
  const float* b0   = (const float*)d_in[4];
  const float* g0   = (const float*)d_in[5];
  const float* be0  = (const float*)d_in[6];
  const float* W1   = (const float*)d_in[7];
  const float* b1   = (const float*)d_in[8];
  const float* g1   = (const float*)d_in[9];
  const float* be1  = (const float*)d_in[10];
  const float* W2   = (const float*)d_in[11];
  const float* b2   = (const float*)d_in[12];
  const float* g2   = (const float*)d_in[13];
  const float* be2  = (const float*)d_in[14];
  const float* Wo   = (const float*)d_in[15];
  const float* bo   = (const float*)d_in[16];
  float* out = (float*)d_out;

  hipLaunchKernelGGL(latent_ode_v6, dim3(64), dim3(256), 0, stream,
                     z0, tt, cond, W0, b0, g0, be0, W1, b1, g1, be1,
                     W2, b2, g2, be2, Wo, bo, out);
}